// Round 8
// baseline (40789.825 us; speedup 1.0000x reference)
//
#include <hip/hip_runtime.h>
#include <math.h>

#define HID 512
#define FEAT 128
#define SEQL 512
#define PREDL 128
#define NWG 256
#define HK 516   // LDS row stride (floats) for h tiles
#define EK 132   // LDS row stride for x/e tiles

typedef float v2f __attribute__((ext_vector_type(2)));

__device__ __forceinline__ float sigf_(float x) { return 1.0f / (1.0f + __expf(-x)); }
__device__ __forceinline__ float tanh_(float x) {
  float ax = fabsf(x);
  float e2 = __expf(-2.0f * ax);
  return copysignf((1.0f - e2) / (1.0f + e2), x);
}
__device__ __forceinline__ v2f mkv2(float a, float b) { v2f r; r[0] = a; r[1] = b; return r; }

__device__ __forceinline__ void stg_sc(float* p, float v) {
  __hip_atomic_store(p, v, __ATOMIC_RELAXED, __HIP_MEMORY_SCOPE_AGENT);
}

// ---------------------------------------------------------------------------
// Producer-stamped barrier (NO atomics): WG i of group g far-stores
// flags[g*32+i] = phase after __syncthreads (h-stores drained per vmcnt(0)
// before s_barrier — verified rounds 3-7). Waiters: lanes 0..31 of wave 0
// poll all 32 flags (one coalesced 128B far load per round) + __ballot;
// lane 0 releases the other 15 waves via an LDS phase flag; those waves
// busy-spin on register FMAs (keeps CU active -> DVFS holds clocks, and
// wake latency ~1 ds_read).
// ---------------------------------------------------------------------------
__device__ __forceinline__ void bar_arrive2(int* __restrict__ bar, int grp,
                                            int idx, int phase, int tid) {
  __syncthreads();
  if (tid == 0)
    __hip_atomic_store(bar + grp * 32 + idx, phase, __ATOMIC_RELAXED,
                       __HIP_MEMORY_SCOPE_AGENT);
  asm volatile("" ::: "memory");
}
__device__ __forceinline__ void bar_wait2(int* __restrict__ bar, int grp,
                                          int phase, int tid,
                                          int* __restrict__ ldsph) {
  asm volatile("" ::: "memory");
  if (tid < 64) {
    int done = 0;
    while (!done) {
      int v = phase;
      if (tid < 32)
        v = __hip_atomic_load(bar + grp * 32 + tid, __ATOMIC_RELAXED,
                              __HIP_MEMORY_SCOPE_AGENT);
      done = (__ballot(v >= phase) == 0xFFFFFFFFFFFFFFFFULL);
    }
    if (tid == 0)
      __hip_atomic_store(ldsph, phase, __ATOMIC_RELAXED,
                         __HIP_MEMORY_SCOPE_WORKGROUP);
  } else {
    float z = 1.0f;
    while (__hip_atomic_load(ldsph, __ATOMIC_RELAXED,
                             __HIP_MEMORY_SCOPE_WORKGROUP) < phase) {
#pragma unroll
      for (int i = 0; i < 64; ++i) z = __builtin_fmaf(z, 1.0000001f, 1.0e-9f);
      asm volatile("" : "+v"(z));
    }
  }
  __syncthreads();
}

// ---- LDS scatter of one dense float4 (h block [512k][16b]) ----------------
__device__ __forceinline__ void scat(float* __restrict__ dst, int idx, float4 v) {
  const int k = idx >> 2, bq = (idx & 3) * 4;
  dst[(bq + 0) * HK + k] = v.x;
  dst[(bq + 1) * HK + k] = v.y;
  dst[(bq + 2) * HK + k] = v.z;
  dst[(bq + 3) * HK + k] = v.w;
}

// dense h-block stage: blk = hX + bt*8192, coherent coalesced dwordx4 reads
__device__ __forceinline__ void stage_hd(float* __restrict__ dst,
                                         const float* __restrict__ blk,
                                         int lane512) {
  const float4* s4 = (const float4*)blk + lane512;
  float4 r0, r1, r2, r3;
  asm volatile(
      "global_load_dwordx4 %0, %4, off sc0 sc1\n\t"
      "global_load_dwordx4 %1, %5, off sc0 sc1\n\t"
      "global_load_dwordx4 %2, %6, off sc0 sc1\n\t"
      "global_load_dwordx4 %3, %7, off sc0 sc1\n\t"
      "s_waitcnt vmcnt(0)"
      : "=&v"(r0), "=&v"(r1), "=&v"(r2), "=&v"(r3)
      : "v"(s4), "v"(s4 + 512), "v"(s4 + 1024), "v"(s4 + 1536)
      : "memory");
  scat(dst, lane512, r0);
  scat(dst, lane512 + 512, r1);
  scat(dst, lane512 + 1024, r2);
  scat(dst, lane512 + 1536, r3);
}

// x tile: plain cached loads -> LDS [16b][EK]
__device__ __forceinline__ void stage_xx(float* __restrict__ dst,
                                         const float* __restrict__ x, int t,
                                         int b0, int lane512) {
  const int bb = lane512 >> 5;
  const int fq = (lane512 & 31) * 4;
  const float4 v =
      *(const float4*)(x + ((size_t)(b0 + bb) * SEQL + t) * FEAT + fq);
  *(float4*)(dst + bb * EK + fq) = v;
}

// ---- packed-FMA GEMV primitives (rounds 4-7 verified) ---------------------
__device__ __forceinline__ void pkf(v2f& a01, v2f& a23, float4 w, float h) {
  v2f hh; hh[0] = h; hh[1] = h;
  v2f lo; lo[0] = w.x; lo[1] = w.y;
  v2f hi; hi[0] = w.z; hi[1] = w.w;
  a01 = __builtin_elementwise_fma(lo, hh, a01);
  a23 = __builtin_elementwise_fma(hi, hh, a23);
}
__device__ __forceinline__ void gemv_fused8(v2f& a01, v2f& a23,
                                            const float4* __restrict__ W8,
                                            size_t base,
                                            const float* __restrict__ rA,
                                            const float* __restrict__ rB,
                                            int k4b, int k4e) {
#pragma unroll 2
  for (int k4 = k4b; k4 < k4e; ++k4) {
    const float4 hA = *(const float4*)(rA + k4 * 4);
    const float4 hB = *(const float4*)(rB + k4 * 4);
    const size_t o = base + (size_t)k4 * 8;
    pkf(a01, a23, W8[o + 0], hA.x); pkf(a01, a23, W8[o + 1], hB.x);
    pkf(a01, a23, W8[o + 2], hA.y); pkf(a01, a23, W8[o + 3], hB.y);
    pkf(a01, a23, W8[o + 4], hA.z); pkf(a01, a23, W8[o + 5], hB.z);
    pkf(a01, a23, W8[o + 6], hA.w); pkf(a01, a23, W8[o + 7], hB.w);
  }
}
__device__ __forceinline__ void gemv_p4(v2f& a01, v2f& a23,
                                        const float4* __restrict__ W4,
                                        size_t base,
                                        const float* __restrict__ row,
                                        int k4b, int k4e) {
#pragma unroll 4
  for (int k4 = k4b; k4 < k4e; ++k4) {
    const float4 h = *(const float4*)(row + k4 * 4);
    const size_t o = base + (size_t)k4 * 4;
    pkf(a01, a23, W4[o + 0], h.x);
    pkf(a01, a23, W4[o + 1], h.y);
    pkf(a01, a23, W4[o + 2], h.z);
    pkf(a01, a23, W4[o + 3], h.w);
  }
}

__device__ __forceinline__ void act_store(v2f a01, v2f a23, float& c_reg,
                                          float* __restrict__ blk, int cit) {
  const float ig = sigf_(a01[0]), fg = sigf_(a01[1]);
  const float gg = tanh_(a23[0]), og = sigf_(a23[1]);
  const float cn = fg * c_reg + ig * gg;
  c_reg = cn;
  stg_sc(blk + cit, og * tanh_(cn));
}

// ---------------------------------------------------------------------------
// Teacher kernel: 256 WG x 1024 thr. crew A (tid<512): LSTM0 2-way k-split.
// crew B: LSTM1(t-1) 2-way k-split.
// ---------------------------------------------------------------------------
__global__ __launch_bounds__(1024, 1) void k_teacher(
    const float* __restrict__ x,
    const float* __restrict__ enc2, const float* __restrict__ enc_b,
    const float* __restrict__ wih04, const float* __restrict__ whh04,
    const float* __restrict__ Wf8,
    const float* __restrict__ bih0, const float* __restrict__ bhh0,
    const float* __restrict__ bih1, const float* __restrict__ bhh1,
    float* __restrict__ h0A, float* __restrict__ h0B,
    float* __restrict__ h1A, float* __restrict__ h1B,
    float* __restrict__ cbuf, int* __restrict__ bar) {
  __shared__ float s_h0[16 * HK];
  __shared__ float s_h1[16 * HK];
  __shared__ float s_x[16 * EK];
  __shared__ float s_e[16 * EK];
  __shared__ float4 s_red4[512];
  __shared__ int lds_ph;

  const int wg = blockIdx.x;
  const int tid = threadIdx.x;
  const int ut = (wg & 7) * 4 + ((wg >> 3) & 3);  // XCD-affine unit tile
  const int bt = wg >> 5;
  const int b0 = bt * 16;
  const int idx32 = wg & 31;
  const int o = tid & 255;
  const int u = o >> 4, b = o & 15;
  const int ug = ut * 16 + u;
  const int cit = ug * 16 + b;           // dense block offset
  const int crewB = tid >> 9;
  const int khalf = (tid >> 8) & 1;
  const int lane512 = tid & 511;

  float* h0b[2] = {h0A, h0B};
  float* h1b[2] = {h1A, h1B};
  const float* sh0row = s_h0 + b * HK;
  const float* sh1row = s_h1 + b * HK;
  const float* serow = s_e + b * EK;

  const float4* W4h = (const float4*)whh04;  // dense whh0, base ug*512
  const float4* W4i = (const float4*)wih04;  // base ug*128
  const float4* W8f = (const float4*)Wf8;    // [wih1|whh1], base ug*1024
  const size_t baseH = (size_t)ug * 512;
  const size_t baseI = (size_t)ug * 128;
  const size_t baseF = (size_t)ug * 1024;

  const float bt00 = bih0[ug] + bhh0[ug];
  const float bt01 = bih0[512 + ug] + bhh0[512 + ug];
  const float bt02 = bih0[1024 + ug] + bhh0[1024 + ug];
  const float bt03 = bih0[1536 + ug] + bhh0[1536 + ug];
  const float b10 = bih1[ug] + bhh1[ug];
  const float b11 = bih1[512 + ug] + bhh1[512 + ug];
  const float b12 = bih1[1024 + ug] + bhh1[1024 + ug];
  const float b13 = bih1[1536 + ug] + bhh1[1536 + ug];

  // encoder role (all 1024 threads): 2 f-outputs for one batch
  const int eb = tid & 15;
  const int f2 = tid >> 4;  // 0..63
  const float4* EF4 = (const float4*)enc2 + (size_t)f2 * 64;
  const float encb0 = enc_b[f2 * 2], encb1 = enc_b[f2 * 2 + 1];
  const float* sxrow = s_x + eb * EK;

  float c_reg = 0.0f;
  int ph = 0;

  if (tid == 0) lds_ph = 0;
  if (tid < 512) stage_xx(s_x, x, 0, b0, lane512);
  __syncthreads();

  for (int t = 0; t < SEQL; ++t) {
    // --- stage h (coherent, dense) ----------------------------------------
    const float* blk = ((tid < 512) ? h0b[(t + 1) & 1] : h1b[t & 1]) + bt * 8192;
    float* dst = (tid < 512) ? s_h0 : s_h1;
    stage_hd(dst, blk, lane512);

    // --- encoder ----------------------------------------------------------
    {
      v2f acc = mkv2(encb0, encb1);
#pragma unroll 8
      for (int k2 = 0; k2 < 64; ++k2) {
        const float4 w = EF4[k2];
        const float hv0 = sxrow[2 * k2], hv1 = sxrow[2 * k2 + 1];
        acc = __builtin_elementwise_fma(mkv2(w.x, w.y), mkv2(hv0, hv0), acc);
        acc = __builtin_elementwise_fma(mkv2(w.z, w.w), mkv2(hv1, hv1), acc);
      }
      s_e[eb * EK + f2 * 2] = acc[0];
      s_e[eb * EK + f2 * 2 + 1] = acc[1];
    }
    __syncthreads();

    // --- cells ------------------------------------------------------------
    v2f a01, a23;
    if (!crewB) {  // LSTM0(t), 2-way k-split
      if (!khalf) {
        a01 = mkv2(bt00, bt01); a23 = mkv2(bt02, bt03);
        gemv_p4(a01, a23, W4h, baseH, sh0row, 0, 80);
      } else {
        a01 = mkv2(0.f, 0.f); a23 = mkv2(0.f, 0.f);
        gemv_p4(a01, a23, W4h, baseH, sh0row, 80, 128);
        gemv_p4(a01, a23, W4i, baseI, serow, 0, 32);
        s_red4[o] = make_float4(a01[0], a01[1], a23[0], a23[1]);
      }
    } else {  // LSTM1(t-1), 2-way k-split
      if (!khalf) {
        a01 = mkv2(b10, b11); a23 = mkv2(b12, b13);
        gemv_fused8(a01, a23, W8f, baseF, sh0row, sh1row, 0, 64);
      } else {
        a01 = mkv2(0.f, 0.f); a23 = mkv2(0.f, 0.f);
        gemv_fused8(a01, a23, W8f, baseF, sh0row, sh1row, 64, 128);
        s_red4[256 + o] = make_float4(a01[0], a01[1], a23[0], a23[1]);
      }
    }
    __syncthreads();
    if (!khalf) {
      const float4 p = s_red4[(crewB ? 256 : 0) + o];
      a01[0] += p.x; a01[1] += p.y; a23[0] += p.z; a23[1] += p.w;
      if (!crewB) act_store(a01, a23, c_reg, h0b[t & 1] + bt * 8192, cit);
      else if (t > 0) act_store(a01, a23, c_reg, h1b[(t + 1) & 1] + bt * 8192, cit);
    }
    bar_arrive2(bar, bt, idx32, ++ph, tid);
    if (tid < 512 && t + 1 < SEQL) stage_xx(s_x, x, t + 1, b0, lane512);
    bar_wait2(bar, bt, ph, tid, &lds_ph);
  }

  // save cell states for the AR kernel
  if (tid < 256) cbuf[(size_t)wg * 256 + o] = c_reg;
  else if (tid >= 512 && tid < 768) cbuf[65536 + (size_t)wg * 256 + o] = c_reg;
}

// ---------------------------------------------------------------------------
// AR kernel: LSTM1(511) then 127 steps of {LSTM0-AR || decode ; LSTM1 4-way}.
// (AR's 2 phases/step are dependency-minimal: h1(t-1)->LSTM0(t)->LSTM1(t).)
// ---------------------------------------------------------------------------
__global__ __launch_bounds__(1024, 1) void k_ar(
    const float* __restrict__ Wa8, const float* __restrict__ Wf8,
    const float* __restrict__ bih0, const float* __restrict__ bhh0,
    const float* __restrict__ bih1, const float* __restrict__ bhh1,
    const float* __restrict__ dec4, const float* __restrict__ dec_b,
    const float* __restrict__ bcomp,
    float* __restrict__ h0A, float* __restrict__ h0B,
    float* __restrict__ h1A, float* __restrict__ h1B,
    float* __restrict__ cbuf, int* __restrict__ bar,
    float* __restrict__ out) {
  __shared__ float s_h0[16 * HK];
  __shared__ float s_h1[16 * HK];
  __shared__ float4 s_red4[768];
  __shared__ int lds_ph;

  const int wg = blockIdx.x;
  const int tid = threadIdx.x;
  const int ut = (wg & 7) * 4 + ((wg >> 3) & 3);
  const int bt = wg >> 5;
  const int b0 = bt * 16;
  const int idx32 = wg & 31;
  const int o = tid & 255;
  const int u = o >> 4, b = o & 15;
  const int ug = ut * 16 + u;
  const int cit = ug * 16 + b;
  const int crewB = tid >> 9;
  const int khalf = (tid >> 8) & 1;
  const int lane512 = tid & 511;
  const int q4 = ((tid >> 8) + 2) & 3;  // owners q4==0 (tid 512..767)

  float* h0b[2] = {h0A, h0B};
  float* h1b[2] = {h1A, h1B};
  const float* sh0row = s_h0 + b * HK;
  const float* sh1row = s_h1 + b * HK;

  const float4* W8a = (const float4*)Wa8;  // [Wcomp|whh0]
  const float4* W8f = (const float4*)Wf8;  // [wih1|whh1]
  const size_t baseG = (size_t)ug * 1024;

  const float ba00 = bih0[ug] + bhh0[ug] + bcomp[ug];
  const float ba01 = bih0[512 + ug] + bhh0[512 + ug] + bcomp[512 + ug];
  const float ba02 = bih0[1024 + ug] + bhh0[1024 + ug] + bcomp[1024 + ug];
  const float ba03 = bih0[1536 + ug] + bhh0[1536 + ug] + bcomp[1536 + ug];
  const float b10 = bih1[ug] + bhh1[ug];
  const float b11 = bih1[512 + ug] + bhh1[512 + ug];
  const float b12 = bih1[1024 + ug] + bhh1[1024 + ug];
  const float b13 = bih1[1536 + ug] + bhh1[1536 + ug];

  // decoder role (crew B): 4 dec rows x 1 batch per thread
  const int cb = tid & 511;
  const int jq = cb >> 4, db = cb & 15;
  const float4* D4 = (const float4*)dec4;
  const size_t baseD = (size_t)jq * 512;
  const float db0 = dec_b[jq * 4], db1 = dec_b[jq * 4 + 1];
  const float db2 = dec_b[jq * 4 + 2], db3 = dec_b[jq * 4 + 3];
  const float* dhrow = s_h1 + db * HK;

  // restore cell state
  float c_reg = 0.0f;
  if (tid < 256) c_reg = cbuf[(size_t)wg * 256 + o];
  else if (tid >= 512 && tid < 768) c_reg = cbuf[65536 + (size_t)wg * 256 + o];

  int ph = 0;
  if (tid == 0) lds_ph = 0;

  // ---- LSTM1(511): A = h0(511)=h0b[1], Hin = h1(510)=h1b[0], 4-way -------
  if (tid < 512) stage_hd(s_h0, h0b[1] + bt * 8192, lane512);
  else stage_hd(s_h1, h1b[0] + bt * 8192, lane512);
  __syncthreads();
  {
    v2f a01, a23;
    if (q4 == 0) { a01 = mkv2(b10, b11); a23 = mkv2(b12, b13); }
    else { a01 = mkv2(0.f, 0.f); a23 = mkv2(0.f, 0.f); }
    gemv_fused8(a01, a23, W8f, baseG, sh0row, sh1row, q4 * 32, q4 * 32 + 32);
    if (q4) s_red4[(q4 - 1) * 256 + o] = make_float4(a01[0], a01[1], a23[0], a23[1]);
    __syncthreads();
    if (q4 == 0) {
      const float4 p0 = s_red4[o], p1 = s_red4[256 + o], p2 = s_red4[512 + o];
      a01[0] += p0.x + p1.x + p2.x; a01[1] += p0.y + p1.y + p2.y;
      a23[0] += p0.z + p1.z + p2.z; a23[1] += p0.w + p1.w + p2.w;
      act_store(a01, a23, c_reg, h1b[1] + bt * 8192, cit);
    }
  }
  bar_arrive2(bar, bt, idx32, ++ph, tid);
  bar_wait2(bar, bt, ph, tid, &lds_ph);

  // ---- autoregressive loop ------------------------------------------------
  for (int t = SEQL; t < SEQL + PREDL - 1; ++t) {
    // phase 1: crew A LSTM0-AR(t) 2-way; crew B decode h1(t-1)
    if (tid < 512) stage_hd(s_h1, h1b[(t + 1) & 1] + bt * 8192, lane512);
    else stage_hd(s_h0, h0b[(t + 1) & 1] + bt * 8192, lane512);
    __syncthreads();
    v2f a01, a23;
    if (!crewB) {
      if (!khalf) { a01 = mkv2(ba00, ba01); a23 = mkv2(ba02, ba03); }
      else { a01 = mkv2(0.f, 0.f); a23 = mkv2(0.f, 0.f); }
      gemv_fused8(a01, a23, W8a, baseG, sh1row, sh0row,
                  khalf ? 64 : 0, khalf ? 128 : 64);
      if (khalf) s_red4[o] = make_float4(a01[0], a01[1], a23[0], a23[1]);
    } else {
      v2f d01 = mkv2(db0, db1), d23 = mkv2(db2, db3);
      gemv_p4(d01, d23, D4, baseD, dhrow, 0, 128);
      *(float4*)(out + ((size_t)(b0 + db) * PREDL + (t - SEQL)) * FEAT + jq * 4) =
          make_float4(d01[0], d01[1], d23[0], d23[1]);
    }
    __syncthreads();
    if (!crewB && !khalf) {
      const float4 p = s_red4[o];
      a01[0] += p.x; a01[1] += p.y; a23[0] += p.z; a23[1] += p.w;
      act_store(a01, a23, c_reg, h0b[t & 1] + bt * 8192, cit);
    }
    bar_arrive2(bar, bt, idx32, ++ph, tid);
    bar_wait2(bar, bt, ph, tid, &lds_ph);

    // phase 2: LSTM1(t) 4-way; Hin = h1(t-1) still in s_h1
    if (tid < 512) stage_hd(s_h0, h0b[t & 1] + bt * 8192, lane512);
    __syncthreads();
    {
      v2f c01, c23;
      if (q4 == 0) { c01 = mkv2(b10, b11); c23 = mkv2(b12, b13); }
      else { c01 = mkv2(0.f, 0.f); c23 = mkv2(0.f, 0.f); }
      gemv_fused8(c01, c23, W8f, baseG, sh0row, sh1row, q4 * 32, q4 * 32 + 32);
      if (q4) s_red4[(q4 - 1) * 256 + o] = make_float4(c01[0], c01[1], c23[0], c23[1]);
      __syncthreads();
      if (q4 == 0) {
        const float4 p0 = s_red4[o], p1 = s_red4[256 + o], p2 = s_red4[512 + o];
        c01[0] += p0.x + p1.x + p2.x; c01[1] += p0.y + p1.y + p2.y;
        c23[0] += p0.z + p1.z + p2.z; c23[1] += p0.w + p1.w + p2.w;
        act_store(c01, c23, c_reg, h1b[t & 1] + bt * 8192, cit);
      }
    }
    bar_arrive2(bar, bt, idx32, ++ph, tid);
    bar_wait2(bar, bt, ph, tid, &lds_ph);
  }

  // final decode: h1(638) = h1b[0], step 127
  if (tid < 512) stage_hd(s_h1, h1b[0] + bt * 8192, lane512);
  __syncthreads();
  if (crewB) {
    v2f d01 = mkv2(db0, db1), d23 = mkv2(db2, db3);
    gemv_p4(d01, d23, D4, baseD, dhrow, 0, 128);
    *(float4*)(out + ((size_t)(b0 + db) * PREDL + (PREDL - 1)) * FEAT + jq * 4) =
        make_float4(d01[0], d01[1], d23[0], d23[1]);
  }
}

// ===== prologue ============================================================
__global__ void k_b1(const float* __restrict__ enc_w,
                     const float* __restrict__ dec_w, float* __restrict__ B1) {
  const int idx = blockIdx.x * 256 + threadIdx.x;
  const int j = idx >> 9, m = idx & 511;
  float acc = 0.0f;
  for (int k = 0; k < FEAT; ++k) acc += enc_w[j * FEAT + k] * dec_w[k * HID + m];
  B1[idx] = acc;
}
__global__ void k_te(const float* __restrict__ enc_w,
                     const float* __restrict__ enc_b,
                     const float* __restrict__ dec_b, float* __restrict__ te) {
  const int j = threadIdx.x;
  float acc = enc_b[j];
  for (int k = 0; k < FEAT; ++k) acc += dec_b[k] * enc_w[j * FEAT + k];
  te[j] = acc;
}
__global__ void k_bcomp(const float* __restrict__ wih0,
                        const float* __restrict__ te, float* __restrict__ bc) {
  const int n = blockIdx.x * 256 + threadIdx.x;
  float acc = 0.0f;
  for (int j = 0; j < FEAT; ++j) acc += wih0[n * FEAT + j] * te[j];
  bc[n] = acc;
}
__global__ void k_wa8(const float* __restrict__ wih0,
                      const float* __restrict__ B1,
                      const float* __restrict__ whh0, float* __restrict__ W) {
  const int idx = blockIdx.x * 256 + threadIdx.x;
  const int uu = idx >> 9, k = idx & 511;
  float c[4];
#pragma unroll
  for (int g = 0; g < 4; ++g) {
    const float* wr = wih0 + ((size_t)(g * 512 + uu)) * FEAT;
    float acc = 0.0f;
    for (int j = 0; j < FEAT; ++j) acc += wr[j] * B1[j * HID + k];
    c[g] = acc;
  }
  float4* op = (float4*)(W + ((size_t)(uu * 512 + k)) * 8);
  op[0] = make_float4(c[0], c[1], c[2], c[3]);
  op[1] = make_float4(whh0[((size_t)uu) * 512 + k],
                      whh0[((size_t)(512 + uu)) * 512 + k],
                      whh0[((size_t)(1024 + uu)) * 512 + k],
                      whh0[((size_t)(1536 + uu)) * 512 + k]);
}
__global__ void k_wf8(const float* __restrict__ wih1,
                      const float* __restrict__ whh1, float* __restrict__ W) {
  const int idx = blockIdx.x * 256 + threadIdx.x;
  const int uu = idx >> 9, k = idx & 511;
  float4* op = (float4*)(W + ((size_t)(uu * 512 + k)) * 8);
  op[0] = make_float4(wih1[((size_t)uu) * 512 + k],
                      wih1[((size_t)(512 + uu)) * 512 + k],
                      wih1[((size_t)(1024 + uu)) * 512 + k],
                      wih1[((size_t)(1536 + uu)) * 512 + k]);
  op[1] = make_float4(whh1[((size_t)uu) * 512 + k],
                      whh1[((size_t)(512 + uu)) * 512 + k],
                      whh1[((size_t)(1024 + uu)) * 512 + k],
                      whh1[((size_t)(1536 + uu)) * 512 + k]);
}
__global__ void k_wih04(const float* __restrict__ wih0, float* __restrict__ W) {
  const int idx = blockIdx.x * 256 + threadIdx.x;  // u(512) x k(128)
  const int uu = idx >> 7, k = idx & 127;
  float4* op = (float4*)(W + ((size_t)idx) * 4);
  op[0] = make_float4(wih0[((size_t)uu) * FEAT + k],
                      wih0[((size_t)(512 + uu)) * FEAT + k],
                      wih0[((size_t)(1024 + uu)) * FEAT + k],
                      wih0[((size_t)(1536 + uu)) * FEAT + k]);
}
// dense whh0 4-interleave: W[(u*512+k)*4+g] = whh0[g*512+u][k]
__global__ void k_whh04(const float* __restrict__ whh0, float* __restrict__ W) {
  const int idx = blockIdx.x * 256 + threadIdx.x;  // u(512) x k(512)
  const int uu = idx >> 9, k = idx & 511;
  float4* op = (float4*)(W + ((size_t)idx) * 4);
  op[0] = make_float4(whh0[((size_t)uu) * 512 + k],
                      whh0[((size_t)(512 + uu)) * 512 + k],
                      whh0[((size_t)(1024 + uu)) * 512 + k],
                      whh0[((size_t)(1536 + uu)) * 512 + k]);
}
__global__ void k_enc2(const float* __restrict__ enc_w, float* __restrict__ W) {
  const int idx = blockIdx.x * 256 + threadIdx.x;  // f2(64) x k(128)
  const int f2 = idx >> 7, k = idx & 127;
  W[(size_t)idx * 2 + 0] = enc_w[((size_t)(f2 * 2 + 0)) * FEAT + k];
  W[(size_t)idx * 2 + 1] = enc_w[((size_t)(f2 * 2 + 1)) * FEAT + k];
}
__global__ void k_dec4(const float* __restrict__ dec_w, float* __restrict__ W) {
  const int idx = blockIdx.x * 256 + threadIdx.x;  // jq(32) x k(512)
  const int jq = idx >> 9, k = idx & 511;
  float4* op = (float4*)(W + ((size_t)idx) * 4);
  op[0] = make_float4(dec_w[((size_t)(jq * 4 + 0)) * HID + k],
                      dec_w[((size_t)(jq * 4 + 1)) * HID + k],
                      dec_w[((size_t)(jq * 4 + 2)) * HID + k],
                      dec_w[((size_t)(jq * 4 + 3)) * HID + k]);
}

// ===== ws layout (floats) ==================================================
#define WS_H0A 0
#define WS_H0B 65536
#define WS_H1A 131072
#define WS_H1B 196608
#define WS_CBUF 262144
#define WS_BART 393216
#define WS_BARA 401408
#define WS_B1 409600
#define WS_TE 475136
#define WS_BCOMP 475264
#define WS_WIH04 477312
#define WS_WHH04 739456
#define WS_ENC2 1788032
#define WS_DEC4 1804416
#define WS_WA8 2066560
#define WS_WF8 4163712

extern "C" void kernel_launch(void* const* d_in, const int* in_sizes, int n_in,
                              void* d_out, int out_size, void* d_ws,
                              size_t ws_size, hipStream_t stream) {
  const float* x     = (const float*)d_in[0];
  const float* enc_w = (const float*)d_in[1];
  const float* enc_b = (const float*)d_in[2];
  const float* dec_w = (const float*)d_in[3];
  const float* dec_b = (const float*)d_in[4];
  const float* wih0  = (const float*)d_in[5];
  const float* whh0  = (const float*)d_in[6];
  const float* bih0  = (const float*)d_in[7];
  const float* bhh0  = (const float*)d_in[8];
  const float* wih1  = (const float*)d_in[9];
  const float* whh1  = (const float*)d_in[10];
  const float* bih1  = (const float*)d_in[11];
  const float* bhh1  = (const float*)d_in[12];
  float* out = (float*)d_out;

  float* ws = (float*)d_ws;
  float* h0A = ws + WS_H0A;
  float* h0B = ws + WS_H0B;
  float* h1A = ws + WS_H1A;
  float* h1B = ws + WS_H1B;
  float* cbuf = ws + WS_CBUF;
  int* barT = (int*)(ws + WS_BART);
  int* barA = (int*)(ws + WS_BARA);
  float* B1 = ws + WS_B1;
  float* te = ws + WS_TE;
  float* bcomp = ws + WS_BCOMP;
  float* wih04 = ws + WS_WIH04;
  float* whh04 = ws + WS_WHH04;
  float* enc2 = ws + WS_ENC2;
  float* dec4 = ws + WS_DEC4;
  float* Wa8 = ws + WS_WA8;
  float* Wf8 = ws + WS_WF8;

  // zero h states + both barrier flag arrays each launch
  (void)hipMemsetAsync(ws, 0, (size_t)262144 * sizeof(float), stream);
  (void)hipMemsetAsync(ws + WS_BART, 0, (size_t)16384 * sizeof(float), stream);

  k_b1<<<256, 256, 0, stream>>>(enc_w, dec_w, B1);
  k_te<<<1, 128, 0, stream>>>(enc_w, enc_b, dec_b, te);
  k_bcomp<<<8, 256, 0, stream>>>(wih0, te, bcomp);
  k_wa8<<<1024, 256, 0, stream>>>(wih0, B1, whh0, Wa8);
  k_wf8<<<1024, 256, 0, stream>>>(wih1, whh1, Wf8);
  k_wih04<<<256, 256, 0, stream>>>(wih0, wih04);
  k_whh04<<<1024, 256, 0, stream>>>(whh0, whh04);
  k_enc2<<<32, 256, 0, stream>>>(enc_w, enc2);
  k_dec4<<<64, 256, 0, stream>>>(dec_w, dec4);

  k_teacher<<<NWG, 1024, 0, stream>>>(
      x, enc2, enc_b, wih04, whh04, Wf8, bih0, bhh0, bih1, bhh1,
      h0A, h0B, h1A, h1B, cbuf, barT);

  k_ar<<<NWG, 1024, 0, stream>>>(
      Wa8, Wf8, bih0, bhh0, bih1, bhh1, dec4, dec_b, bcomp,
      h0A, h0B, h1A, h1B, cbuf, barA, out);
}

// Round 11
// 40751.276 us; speedup vs baseline: 1.0009x; 1.0009x over previous
//
#include <hip/hip_runtime.h>
#include <math.h>

#define HID 512
#define FEAT 128
#define SEQL 512
#define PREDL 128
#define NWG 256
#define HK 516   // LDS row stride (floats) for h tiles
#define EK 132   // LDS row stride for x/e tiles

typedef float v2f __attribute__((ext_vector_type(2)));

__device__ __forceinline__ float sigf_(float x) { return 1.0f / (1.0f + __expf(-x)); }
__device__ __forceinline__ float tanh_(float x) {
  float ax = fabsf(x);
  float e2 = __expf(-2.0f * ax);
  return copysignf((1.0f - e2) / (1.0f + e2), x);
}
__device__ __forceinline__ v2f mkv2(float a, float b) { v2f r; r[0] = a; r[1] = b; return r; }

__device__ __forceinline__ void stg_sc(float* p, float v) {
  __hip_atomic_store(p, v, __ATOMIC_RELAXED, __HIP_MEMORY_SCOPE_AGENT);
}

// ---------------------------------------------------------------------------
// Producer-stamped barrier (NO atomics) — round-8 verified. WG i of group g
// far-stores flags[g*32+i]=phase after __syncthreads (vmcnt(0)-drained).
// Waiters: lanes 0..31 of wave 0 poll all 32 flags (one coalesced 128B far
// load per round) + __ballot, with s_sleep backoff; lane 0 releases the other
// 15 waves via an LDS phase flag (FMA-ballast spin).
// ---------------------------------------------------------------------------
__device__ __forceinline__ void bar_arrive2(int* __restrict__ bar, int grp,
                                            int idx, int phase, int tid) {
  __syncthreads();
  if (tid == 0)
    __hip_atomic_store(bar + grp * 32 + idx, phase, __ATOMIC_RELAXED,
                       __HIP_MEMORY_SCOPE_AGENT);
  asm volatile("" ::: "memory");
}
__device__ __forceinline__ void bar_wait2(int* __restrict__ bar, int grp,
                                          int phase, int tid,
                                          int* __restrict__ ldsph) {
  asm volatile("" ::: "memory");
  if (tid < 64) {
    for (;;) {
      int v = phase;
      if (tid < 32)
        v = __hip_atomic_load(bar + grp * 32 + tid, __ATOMIC_RELAXED,
                              __HIP_MEMORY_SCOPE_AGENT);
      if (__ballot(v >= phase) == 0xFFFFFFFFFFFFFFFFULL) break;
      __builtin_amdgcn_s_sleep(8);  // ~512cy backoff: cut fabric poll spam
    }
    if (tid == 0)
      __hip_atomic_store(ldsph, phase, __ATOMIC_RELAXED,
                         __HIP_MEMORY_SCOPE_WORKGROUP);
  } else {
    float z = 1.0f;
    while (__hip_atomic_load(ldsph, __ATOMIC_RELAXED,
                             __HIP_MEMORY_SCOPE_WORKGROUP) < phase) {
#pragma unroll
      for (int i = 0; i < 64; ++i) z = __builtin_fmaf(z, 1.0000001f, 1.0e-9f);
      asm volatile("" : "+v"(z));
    }
  }
  __syncthreads();
}

// ---- LDS scatter of one dense float4 (h block [512k][16b]) ----------------
__device__ __forceinline__ void scat(float* __restrict__ dst, int idx, float4 v) {
  const int k = idx >> 2, bq = (idx & 3) * 4;
  dst[(bq + 0) * HK + k] = v.x;
  dst[(bq + 1) * HK + k] = v.y;
  dst[(bq + 2) * HK + k] = v.z;
  dst[(bq + 3) * HK + k] = v.w;
}

// dense h-block stage (issue+wait fused) — used by AR kernel (no overlap work)
__device__ __forceinline__ void stage_hd(float* __restrict__ dst,
                                         const float* __restrict__ blk,
                                         int lane512) {
  const float4* s4 = (const float4*)blk + lane512;
  float4 r0, r1, r2, r3;
  asm volatile(
      "global_load_dwordx4 %0, %4, off sc0 sc1\n\t"
      "global_load_dwordx4 %1, %5, off sc0 sc1\n\t"
      "global_load_dwordx4 %2, %6, off sc0 sc1\n\t"
      "global_load_dwordx4 %3, %7, off sc0 sc1\n\t"
      "s_waitcnt vmcnt(0)"
      : "=&v"(r0), "=&v"(r1), "=&v"(r2), "=&v"(r3)
      : "v"(s4), "v"(s4 + 512), "v"(s4 + 1024), "v"(s4 + 1536)
      : "memory");
  scat(dst, lane512, r0);
  scat(dst, lane512 + 512, r1);
  scat(dst, lane512 + 1024, r2);
  scat(dst, lane512 + 1536, r3);
}

// issue-only variant: NO waitcnt inside — the compiler inserts progressive
// s_waitcnt vmcnt(N) before the first USE of each output (scat), letting
// independent work (encoder) run in the load shadow. No tied operands.
__device__ __forceinline__ void stage_issue(const float* __restrict__ blk,
                                            int lane512, float4& r0, float4& r1,
                                            float4& r2, float4& r3) {
  const float4* s4 = (const float4*)blk + lane512;
  asm volatile(
      "global_load_dwordx4 %0, %4, off sc0 sc1\n\t"
      "global_load_dwordx4 %1, %5, off sc0 sc1\n\t"
      "global_load_dwordx4 %2, %6, off sc0 sc1\n\t"
      "global_load_dwordx4 %3, %7, off sc0 sc1"
      : "=&v"(r0), "=&v"(r1), "=&v"(r2), "=&v"(r3)
      : "v"(s4), "v"(s4 + 512), "v"(s4 + 1024), "v"(s4 + 1536)
      : "memory");
}

// x tile: plain cached loads -> LDS [16b][EK]
__device__ __forceinline__ void stage_xx(float* __restrict__ dst,
                                         const float* __restrict__ x, int t,
                                         int b0, int lane512) {
  const int bb = lane512 >> 5;
  const int fq = (lane512 & 31) * 4;
  const float4 v =
      *(const float4*)(x + ((size_t)(b0 + bb) * SEQL + t) * FEAT + fq);
  *(float4*)(dst + bb * EK + fq) = v;
}

// ---- packed-FMA GEMV primitives (rounds 4-8 verified) ---------------------
__device__ __forceinline__ void pkf(v2f& a01, v2f& a23, float4 w, float h) {
  v2f hh; hh[0] = h; hh[1] = h;
  v2f lo; lo[0] = w.x; lo[1] = w.y;
  v2f hi; hi[0] = w.z; hi[1] = w.w;
  a01 = __builtin_elementwise_fma(lo, hh, a01);
  a23 = __builtin_elementwise_fma(hi, hh, a23);
}
__device__ __forceinline__ void gemv_fused8(v2f& a01, v2f& a23,
                                            const float4* __restrict__ W8,
                                            size_t base,
                                            const float* __restrict__ rA,
                                            const float* __restrict__ rB,
                                            int k4b, int k4e) {
#pragma unroll 2
  for (int k4 = k4b; k4 < k4e; ++k4) {
    const float4 hA = *(const float4*)(rA + k4 * 4);
    const float4 hB = *(const float4*)(rB + k4 * 4);
    const size_t o = base + (size_t)k4 * 8;
    pkf(a01, a23, W8[o + 0], hA.x); pkf(a01, a23, W8[o + 1], hB.x);
    pkf(a01, a23, W8[o + 2], hA.y); pkf(a01, a23, W8[o + 3], hB.y);
    pkf(a01, a23, W8[o + 4], hA.z); pkf(a01, a23, W8[o + 5], hB.z);
    pkf(a01, a23, W8[o + 6], hA.w); pkf(a01, a23, W8[o + 7], hB.w);
  }
}
__device__ __forceinline__ void gemv_p4(v2f& a01, v2f& a23,
                                        const float4* __restrict__ W4,
                                        size_t base,
                                        const float* __restrict__ row,
                                        int k4b, int k4e) {
#pragma unroll 4
  for (int k4 = k4b; k4 < k4e; ++k4) {
    const float4 h = *(const float4*)(row + k4 * 4);
    const size_t o = base + (size_t)k4 * 4;
    pkf(a01, a23, W4[o + 0], h.x);
    pkf(a01, a23, W4[o + 1], h.y);
    pkf(a01, a23, W4[o + 2], h.z);
    pkf(a01, a23, W4[o + 3], h.w);
  }
}

__device__ __forceinline__ void act_store(v2f a01, v2f a23, float& c_reg,
                                          float* __restrict__ blk, int cit) {
  const float ig = sigf_(a01[0]), fg = sigf_(a01[1]);
  const float gg = tanh_(a23[0]), og = sigf_(a23[1]);
  const float cn = fg * c_reg + ig * gg;
  c_reg = cn;
  stg_sc(blk + cit, og * tanh_(cn));
}

// ---------------------------------------------------------------------------
// Teacher kernel: 256 WG x 1024 thr. crew A (tid<512): LSTM0 2-way k-split.
// crew B: LSTM1(t-1) 2-way k-split. h-loads issued BEFORE the encoder so the
// encoder FMAs run in the far-load shadow (compiler inserts the vmcnt waits
// before the LDS scatter uses).
// ---------------------------------------------------------------------------
__global__ __launch_bounds__(1024, 1) void k_teacher(
    const float* __restrict__ x,
    const float* __restrict__ enc2, const float* __restrict__ enc_b,
    const float* __restrict__ wih04, const float* __restrict__ whh04,
    const float* __restrict__ Wf8,
    const float* __restrict__ bih0, const float* __restrict__ bhh0,
    const float* __restrict__ bih1, const float* __restrict__ bhh1,
    float* __restrict__ h0A, float* __restrict__ h0B,
    float* __restrict__ h1A, float* __restrict__ h1B,
    float* __restrict__ cbuf, int* __restrict__ bar) {
  __shared__ float s_h0[16 * HK];
  __shared__ float s_h1[16 * HK];
  __shared__ float s_x[16 * EK];
  __shared__ float s_e[16 * EK];
  __shared__ float4 s_red4[512];
  __shared__ int lds_ph;

  const int wg = blockIdx.x;
  const int tid = threadIdx.x;
  const int ut = (wg & 7) * 4 + ((wg >> 3) & 3);  // XCD-affine unit tile
  const int bt = wg >> 5;
  const int b0 = bt * 16;
  const int idx32 = wg & 31;
  const int o = tid & 255;
  const int u = o >> 4, b = o & 15;
  const int ug = ut * 16 + u;
  const int cit = ug * 16 + b;           // dense block offset
  const int crewB = tid >> 9;
  const int khalf = (tid >> 8) & 1;
  const int lane512 = tid & 511;

  float* h0b[2] = {h0A, h0B};
  float* h1b[2] = {h1A, h1B};
  const float* sh0row = s_h0 + b * HK;
  const float* sh1row = s_h1 + b * HK;
  const float* serow = s_e + b * EK;

  const float4* W4h = (const float4*)whh04;  // dense whh0, base ug*512
  const float4* W4i = (const float4*)wih04;  // base ug*128
  const float4* W8f = (const float4*)Wf8;    // [wih1|whh1], base ug*1024
  const size_t baseH = (size_t)ug * 512;
  const size_t baseI = (size_t)ug * 128;
  const size_t baseF = (size_t)ug * 1024;

  const float bt00 = bih0[ug] + bhh0[ug];
  const float bt01 = bih0[512 + ug] + bhh0[512 + ug];
  const float bt02 = bih0[1024 + ug] + bhh0[1024 + ug];
  const float bt03 = bih0[1536 + ug] + bhh0[1536 + ug];
  const float b10 = bih1[ug] + bhh1[ug];
  const float b11 = bih1[512 + ug] + bhh1[512 + ug];
  const float b12 = bih1[1024 + ug] + bhh1[1024 + ug];
  const float b13 = bih1[1536 + ug] + bhh1[1536 + ug];

  // encoder role (all 1024 threads): 2 f-outputs for one batch
  const int eb = tid & 15;
  const int f2 = tid >> 4;  // 0..63
  const float4* EF4 = (const float4*)enc2 + (size_t)f2 * 64;
  const float encb0 = enc_b[f2 * 2], encb1 = enc_b[f2 * 2 + 1];
  const float* sxrow = s_x + eb * EK;

  float c_reg = 0.0f;
  int ph = 0;

  if (tid == 0) lds_ph = 0;
  if (tid < 512) stage_xx(s_x, x, 0, b0, lane512);
  __syncthreads();

  for (int t = 0; t < SEQL; ++t) {
    // --- issue far h-loads (no wait) ---------------------------------------
    const float* blk = ((tid < 512) ? h0b[(t + 1) & 1] : h1b[t & 1]) + bt * 8192;
    float4 r0, r1, r2, r3;
    stage_issue(blk, lane512, r0, r1, r2, r3);

    // --- encoder runs in the load shadow -----------------------------------
    {
      v2f acc = mkv2(encb0, encb1);
#pragma unroll 8
      for (int k2 = 0; k2 < 64; ++k2) {
        const float4 w = EF4[k2];
        const float hv0 = sxrow[2 * k2], hv1 = sxrow[2 * k2 + 1];
        acc = __builtin_elementwise_fma(mkv2(w.x, w.y), mkv2(hv0, hv0), acc);
        acc = __builtin_elementwise_fma(mkv2(w.z, w.w), mkv2(hv1, hv1), acc);
      }
      s_e[eb * EK + f2 * 2] = acc[0];
      s_e[eb * EK + f2 * 2 + 1] = acc[1];
    }

    // --- consume loads (compiler-inserted vmcnt waits) + scatter -----------
    float* dst = (tid < 512) ? s_h0 : s_h1;
    scat(dst, lane512, r0);
    scat(dst, lane512 + 512, r1);
    scat(dst, lane512 + 1024, r2);
    scat(dst, lane512 + 1536, r3);
    __syncthreads();

    // --- cells ------------------------------------------------------------
    v2f a01, a23;
    if (!crewB) {  // LSTM0(t), 2-way k-split
      if (!khalf) {
        a01 = mkv2(bt00, bt01); a23 = mkv2(bt02, bt03);
        gemv_p4(a01, a23, W4h, baseH, sh0row, 0, 80);
      } else {
        a01 = mkv2(0.f, 0.f); a23 = mkv2(0.f, 0.f);
        gemv_p4(a01, a23, W4h, baseH, sh0row, 80, 128);
        gemv_p4(a01, a23, W4i, baseI, serow, 0, 32);
        s_red4[o] = make_float4(a01[0], a01[1], a23[0], a23[1]);
      }
    } else {  // LSTM1(t-1), 2-way k-split
      if (!khalf) {
        a01 = mkv2(b10, b11); a23 = mkv2(b12, b13);
        gemv_fused8(a01, a23, W8f, baseF, sh0row, sh1row, 0, 64);
      } else {
        a01 = mkv2(0.f, 0.f); a23 = mkv2(0.f, 0.f);
        gemv_fused8(a01, a23, W8f, baseF, sh0row, sh1row, 64, 128);
        s_red4[256 + o] = make_float4(a01[0], a01[1], a23[0], a23[1]);
      }
    }
    __syncthreads();
    if (!khalf) {
      const float4 p = s_red4[(crewB ? 256 : 0) + o];
      a01[0] += p.x; a01[1] += p.y; a23[0] += p.z; a23[1] += p.w;
      if (!crewB) act_store(a01, a23, c_reg, h0b[t & 1] + bt * 8192, cit);
      else if (t > 0) act_store(a01, a23, c_reg, h1b[(t + 1) & 1] + bt * 8192, cit);
    }
    bar_arrive2(bar, bt, idx32, ++ph, tid);
    if (tid < 512 && t + 1 < SEQL) stage_xx(s_x, x, t + 1, b0, lane512);
    bar_wait2(bar, bt, ph, tid, &lds_ph);
  }

  // save cell states for the AR kernel
  if (tid < 256) cbuf[(size_t)wg * 256 + o] = c_reg;
  else if (tid >= 512 && tid < 768) cbuf[65536 + (size_t)wg * 256 + o] = c_reg;
}

// ---------------------------------------------------------------------------
// AR kernel: LSTM1(511) then 127 steps of {LSTM0-AR || decode ; LSTM1 4-way}.
// (AR's 2 phases/step are dependency-minimal: h1(t-1)->LSTM0(t)->LSTM1(t).)
// ---------------------------------------------------------------------------
__global__ __launch_bounds__(1024, 1) void k_ar(
    const float* __restrict__ Wa8, const float* __restrict__ Wf8,
    const float* __restrict__ bih0, const float* __restrict__ bhh0,
    const float* __restrict__ bih1, const float* __restrict__ bhh1,
    const float* __restrict__ dec4, const float* __restrict__ dec_b,
    const float* __restrict__ bcomp,
    float* __restrict__ h0A, float* __restrict__ h0B,
    float* __restrict__ h1A, float* __restrict__ h1B,
    float* __restrict__ cbuf, int* __restrict__ bar,
    float* __restrict__ out) {
  __shared__ float s_h0[16 * HK];
  __shared__ float s_h1[16 * HK];
  __shared__ float4 s_red4[768];
  __shared__ int lds_ph;

  const int wg = blockIdx.x;
  const int tid = threadIdx.x;
  const int ut = (wg & 7) * 4 + ((wg >> 3) & 3);
  const int bt = wg >> 5;
  const int b0 = bt * 16;
  const int idx32 = wg & 31;
  const int o = tid & 255;
  const int u = o >> 4, b = o & 15;
  const int ug = ut * 16 + u;
  const int cit = ug * 16 + b;
  const int crewB = tid >> 9;
  const int khalf = (tid >> 8) & 1;
  const int lane512 = tid & 511;
  const int q4 = ((tid >> 8) + 2) & 3;  // owners q4==0 (tid 512..767)

  float* h0b[2] = {h0A, h0B};
  float* h1b[2] = {h1A, h1B};
  const float* sh0row = s_h0 + b * HK;
  const float* sh1row = s_h1 + b * HK;

  const float4* W8a = (const float4*)Wa8;  // [Wcomp|whh0]
  const float4* W8f = (const float4*)Wf8;  // [wih1|whh1]
  const size_t baseG = (size_t)ug * 1024;

  const float ba00 = bih0[ug] + bhh0[ug] + bcomp[ug];
  const float ba01 = bih0[512 + ug] + bhh0[512 + ug] + bcomp[512 + ug];
  const float ba02 = bih0[1024 + ug] + bhh0[1024 + ug] + bcomp[1024 + ug];
  const float ba03 = bih0[1536 + ug] + bhh0[1536 + ug] + bcomp[1536 + ug];
  const float b10 = bih1[ug] + bhh1[ug];
  const float b11 = bih1[512 + ug] + bhh1[512 + ug];
  const float b12 = bih1[1024 + ug] + bhh1[1024 + ug];
  const float b13 = bih1[1536 + ug] + bhh1[1536 + ug];

  // decoder role (crew B): 4 dec rows x 1 batch per thread
  const int cb = tid & 511;
  const int jq = cb >> 4, db = cb & 15;
  const float4* D4 = (const float4*)dec4;
  const size_t baseD = (size_t)jq * 512;
  const float db0 = dec_b[jq * 4], db1 = dec_b[jq * 4 + 1];
  const float db2 = dec_b[jq * 4 + 2], db3 = dec_b[jq * 4 + 3];
  const float* dhrow = s_h1 + db * HK;

  // restore cell state
  float c_reg = 0.0f;
  if (tid < 256) c_reg = cbuf[(size_t)wg * 256 + o];
  else if (tid >= 512 && tid < 768) c_reg = cbuf[65536 + (size_t)wg * 256 + o];

  int ph = 0;
  if (tid == 0) lds_ph = 0;

  // ---- LSTM1(511): A = h0(511)=h0b[1], Hin = h1(510)=h1b[0], 4-way -------
  if (tid < 512) stage_hd(s_h0, h0b[1] + bt * 8192, lane512);
  else stage_hd(s_h1, h1b[0] + bt * 8192, lane512);
  __syncthreads();
  {
    v2f a01, a23;
    if (q4 == 0) { a01 = mkv2(b10, b11); a23 = mkv2(b12, b13); }
    else { a01 = mkv2(0.f, 0.f); a23 = mkv2(0.f, 0.f); }
    gemv_fused8(a01, a23, W8f, baseG, sh0row, sh1row, q4 * 32, q4 * 32 + 32);
    if (q4) s_red4[(q4 - 1) * 256 + o] = make_float4(a01[0], a01[1], a23[0], a23[1]);
    __syncthreads();
    if (q4 == 0) {
      const float4 p0 = s_red4[o], p1 = s_red4[256 + o], p2 = s_red4[512 + o];
      a01[0] += p0.x + p1.x + p2.x; a01[1] += p0.y + p1.y + p2.y;
      a23[0] += p0.z + p1.z + p2.z; a23[1] += p0.w + p1.w + p2.w;
      act_store(a01, a23, c_reg, h1b[1] + bt * 8192, cit);
    }
  }
  bar_arrive2(bar, bt, idx32, ++ph, tid);
  bar_wait2(bar, bt, ph, tid, &lds_ph);

  // ---- autoregressive loop ------------------------------------------------
  for (int t = SEQL; t < SEQL + PREDL - 1; ++t) {
    // phase 1: crew A LSTM0-AR(t) 2-way; crew B decode h1(t-1)
    if (tid < 512) stage_hd(s_h1, h1b[(t + 1) & 1] + bt * 8192, lane512);
    else stage_hd(s_h0, h0b[(t + 1) & 1] + bt * 8192, lane512);
    __syncthreads();
    v2f a01, a23;
    if (!crewB) {
      if (!khalf) { a01 = mkv2(ba00, ba01); a23 = mkv2(ba02, ba03); }
      else { a01 = mkv2(0.f, 0.f); a23 = mkv2(0.f, 0.f); }
      gemv_fused8(a01, a23, W8a, baseG, sh1row, sh0row,
                  khalf ? 64 : 0, khalf ? 128 : 64);
      if (khalf) s_red4[o] = make_float4(a01[0], a01[1], a23[0], a23[1]);
    } else {
      v2f d01 = mkv2(db0, db1), d23 = mkv2(db2, db3);
      gemv_p4(d01, d23, D4, baseD, dhrow, 0, 128);
      *(float4*)(out + ((size_t)(b0 + db) * PREDL + (t - SEQL)) * FEAT + jq * 4) =
          make_float4(d01[0], d01[1], d23[0], d23[1]);
    }
    __syncthreads();
    if (!crewB && !khalf) {
      const float4 p = s_red4[o];
      a01[0] += p.x; a01[1] += p.y; a23[0] += p.z; a23[1] += p.w;
      act_store(a01, a23, c_reg, h0b[t & 1] + bt * 8192, cit);
    }
    bar_arrive2(bar, bt, idx32, ++ph, tid);
    bar_wait2(bar, bt, ph, tid, &lds_ph);

    // phase 2: LSTM1(t) 4-way; Hin = h1(t-1) still in s_h1
    if (tid < 512) stage_hd(s_h0, h0b[t & 1] + bt * 8192, lane512);
    __syncthreads();
    {
      v2f c01, c23;
      if (q4 == 0) { c01 = mkv2(b10, b11); c23 = mkv2(b12, b13); }
      else { c01 = mkv2(0.f, 0.f); c23 = mkv2(0.f, 0.f); }
      gemv_fused8(c01, c23, W8f, baseG, sh0row, sh1row, q4 * 32, q4 * 32 + 32);
      if (q4) s_red4[(q4 - 1) * 256 + o] = make_float4(c01[0], c01[1], c23[0], c23[1]);
      __syncthreads();
      if (q4 == 0) {
        const float4 p0 = s_red4[o], p1 = s_red4[256 + o], p2 = s_red4[512 + o];
        c01[0] += p0.x + p1.x + p2.x; c01[1] += p0.y + p1.y + p2.y;
        c23[0] += p0.z + p1.z + p2.z; c23[1] += p0.w + p1.w + p2.w;
        act_store(c01, c23, c_reg, h1b[t & 1] + bt * 8192, cit);
      }
    }
    bar_arrive2(bar, bt, idx32, ++ph, tid);
    bar_wait2(bar, bt, ph, tid, &lds_ph);
  }

  // final decode: h1(638) = h1b[0], step 127
  if (tid < 512) stage_hd(s_h1, h1b[0] + bt * 8192, lane512);
  __syncthreads();
  if (crewB) {
    v2f d01 = mkv2(db0, db1), d23 = mkv2(db2, db3);
    gemv_p4(d01, d23, D4, baseD, dhrow, 0, 128);
    *(float4*)(out + ((size_t)(b0 + db) * PREDL + (PREDL - 1)) * FEAT + jq * 4) =
        make_float4(d01[0], d01[1], d23[0], d23[1]);
  }
}

// ===== prologue ============================================================
__global__ void k_b1(const float* __restrict__ enc_w,
                     const float* __restrict__ dec_w, float* __restrict__ B1) {
  const int idx = blockIdx.x * 256 + threadIdx.x;
  const int j = idx >> 9, m = idx & 511;
  float acc = 0.0f;
  for (int k = 0; k < FEAT; ++k) acc += enc_w[j * FEAT + k] * dec_w[k * HID + m];
  B1[idx] = acc;
}
__global__ void k_te(const float* __restrict__ enc_w,
                     const float* __restrict__ enc_b,
                     const float* __restrict__ dec_b, float* __restrict__ te) {
  const int j = threadIdx.x;
  float acc = enc_b[j];
  for (int k = 0; k < FEAT; ++k) acc += dec_b[k] * enc_w[j * FEAT + k];
  te[j] = acc;
}
__global__ void k_bcomp(const float* __restrict__ wih0,
                        const float* __restrict__ te, float* __restrict__ bc) {
  const int n = blockIdx.x * 256 + threadIdx.x;
  float acc = 0.0f;
  for (int j = 0; j < FEAT; ++j) acc += wih0[n * FEAT + j] * te[j];
  bc[n] = acc;
}
__global__ void k_wa8(const float* __restrict__ wih0,
                      const float* __restrict__ B1,
                      const float* __restrict__ whh0, float* __restrict__ W) {
  const int idx = blockIdx.x * 256 + threadIdx.x;
  const int uu = idx >> 9, k = idx & 511;
  float c[4];
#pragma unroll
  for (int g = 0; g < 4; ++g) {
    const float* wr = wih0 + ((size_t)(g * 512 + uu)) * FEAT;
    float acc = 0.0f;
    for (int j = 0; j < FEAT; ++j) acc += wr[j] * B1[j * HID + k];
    c[g] = acc;
  }
  float4* op = (float4*)(W + ((size_t)(uu * 512 + k)) * 8);
  op[0] = make_float4(c[0], c[1], c[2], c[3]);
  op[1] = make_float4(whh0[((size_t)uu) * 512 + k],
                      whh0[((size_t)(512 + uu)) * 512 + k],
                      whh0[((size_t)(1024 + uu)) * 512 + k],
                      whh0[((size_t)(1536 + uu)) * 512 + k]);
}
__global__ void k_wf8(const float* __restrict__ wih1,
                      const float* __restrict__ whh1, float* __restrict__ W) {
  const int idx = blockIdx.x * 256 + threadIdx.x;
  const int uu = idx >> 9, k = idx & 511;
  float4* op = (float4*)(W + ((size_t)(uu * 512 + k)) * 8);
  op[0] = make_float4(wih1[((size_t)uu) * 512 + k],
                      wih1[((size_t)(512 + uu)) * 512 + k],
                      wih1[((size_t)(1024 + uu)) * 512 + k],
                      wih1[((size_t)(1536 + uu)) * 512 + k]);
  op[1] = make_float4(whh1[((size_t)uu) * 512 + k],
                      whh1[((size_t)(512 + uu)) * 512 + k],
                      whh1[((size_t)(1024 + uu)) * 512 + k],
                      whh1[((size_t)(1536 + uu)) * 512 + k]);
}
__global__ void k_wih04(const float* __restrict__ wih0, float* __restrict__ W) {
  const int idx = blockIdx.x * 256 + threadIdx.x;  // u(512) x k(128)
  const int uu = idx >> 7, k = idx & 127;
  float4* op = (float4*)(W + ((size_t)idx) * 4);
  op[0] = make_float4(wih0[((size_t)uu) * FEAT + k],
                      wih0[((size_t)(512 + uu)) * FEAT + k],
                      wih0[((size_t)(1024 + uu)) * FEAT + k],
                      wih0[((size_t)(1536 + uu)) * FEAT + k]);
}
// dense whh0 4-interleave: W[(u*512+k)*4+g] = whh0[g*512+u][k]
__global__ void k_whh04(const float* __restrict__ whh0, float* __restrict__ W) {
  const int idx = blockIdx.x * 256 + threadIdx.x;  // u(512) x k(512)
  const int uu = idx >> 9, k = idx & 511;
  float4* op = (float4*)(W + ((size_t)idx) * 4);
  op[0] = make_float4(whh0[((size_t)uu) * 512 + k],
                      whh0[((size_t)(512 + uu)) * 512 + k],
                      whh0[((size_t)(1024 + uu)) * 512 + k],
                      whh0[((size_t)(1536 + uu)) * 512 + k]);
}
__global__ void k_enc2(const float* __restrict__ enc_w, float* __restrict__ W) {
  const int idx = blockIdx.x * 256 + threadIdx.x;  // f2(64) x k(128)
  const int f2 = idx >> 7, k = idx & 127;
  W[(size_t)idx * 2 + 0] = enc_w[((size_t)(f2 * 2 + 0)) * FEAT + k];
  W[(size_t)idx * 2 + 1] = enc_w[((size_t)(f2 * 2 + 1)) * FEAT + k];
}
__global__ void k_dec4(const float* __restrict__ dec_w, float* __restrict__ W) {
  const int idx = blockIdx.x * 256 + threadIdx.x;  // jq(32) x k(512)
  const int jq = idx >> 9, k = idx & 511;
  float4* op = (float4*)(W + ((size_t)idx) * 4);
  op[0] = make_float4(dec_w[((size_t)(jq * 4 + 0)) * HID + k],
                      dec_w[((size_t)(jq * 4 + 1)) * HID + k],
                      dec_w[((size_t)(jq * 4 + 2)) * HID + k],
                      dec_w[((size_t)(jq * 4 + 3)) * HID + k]);
}

// ===== ws layout (floats) ==================================================
#define WS_H0A 0
#define WS_H0B 65536
#define WS_H1A 131072
#define WS_H1B 196608
#define WS_CBUF 262144
#define WS_BART 393216
#define WS_BARA 401408
#define WS_B1 409600
#define WS_TE 475136
#define WS_BCOMP 475264
#define WS_WIH04 477312
#define WS_WHH04 739456
#define WS_ENC2 1788032
#define WS_DEC4 1804416
#define WS_WA8 2066560
#define WS_WF8 4163712

extern "C" void kernel_launch(void* const* d_in, const int* in_sizes, int n_in,
                              void* d_out, int out_size, void* d_ws,
                              size_t ws_size, hipStream_t stream) {
  const float* x     = (const float*)d_in[0];
  const float* enc_w = (const float*)d_in[1];
  const float* enc_b = (const float*)d_in[2];
  const float* dec_w = (const float*)d_in[3];
  const float* dec_b = (const float*)d_in[4];
  const float* wih0  = (const float*)d_in[5];
  const float* whh0  = (const float*)d_in[6];
  const float* bih0  = (const float*)d_in[7];
  const float* bhh0  = (const float*)d_in[8];
  const float* wih1  = (const float*)d_in[9];
  const float* whh1  = (const float*)d_in[10];
  const float* bih1  = (const float*)d_in[11];
  const float* bhh1  = (const float*)d_in[12];
  float* out = (float*)d_out;

  float* ws = (float*)d_ws;
  float* h0A = ws + WS_H0A;
  float* h0B = ws + WS_H0B;
  float* h1A = ws + WS_H1A;
  float* h1B = ws + WS_H1B;
  float* cbuf = ws + WS_CBUF;
  int* barT = (int*)(ws + WS_BART);
  int* barA = (int*)(ws + WS_BARA);
  float* B1 = ws + WS_B1;
  float* te = ws + WS_TE;
  float* bcomp = ws + WS_BCOMP;
  float* wih04 = ws + WS_WIH04;
  float* whh04 = ws + WS_WHH04;
  float* enc2 = ws + WS_ENC2;
  float* dec4 = ws + WS_DEC4;
  float* Wa8 = ws + WS_WA8;
  float* Wf8 = ws + WS_WF8;

  // zero h states + both barrier flag arrays each launch
  (void)hipMemsetAsync(ws, 0, (size_t)262144 * sizeof(float), stream);
  (void)hipMemsetAsync(ws + WS_BART, 0, (size_t)16384 * sizeof(float), stream);

  k_b1<<<256, 256, 0, stream>>>(enc_w, dec_w, B1);
  k_te<<<1, 128, 0, stream>>>(enc_w, enc_b, dec_b, te);
  k_bcomp<<<8, 256, 0, stream>>>(wih0, te, bcomp);
  k_wa8<<<1024, 256, 0, stream>>>(wih0, B1, whh0, Wa8);
  k_wf8<<<1024, 256, 0, stream>>>(wih1, whh1, Wf8);
  k_wih04<<<256, 256, 0, stream>>>(wih0, wih04);
  k_whh04<<<1024, 256, 0, stream>>>(whh0, whh04);
  k_enc2<<<32, 256, 0, stream>>>(enc_w, enc2);
  k_dec4<<<64, 256, 0, stream>>>(dec_w, dec4);

  k_teacher<<<NWG, 1024, 0, stream>>>(
      x, enc2, enc_b, wih04, whh04, Wf8, bih0, bhh0, bih1, bhh1,
      h0A, h0B, h1A, h1B, cbuf, barT);

  k_ar<<<NWG, 1024, 0, stream>>>(
      Wa8, Wf8, bih0, bhh0, bih1, bhh1, dec4, dec_b, bcomp,
      h0A, h0B, h1A, h1B, cbuf, barA, out);
}

// Round 12
// 37975.336 us; speedup vs baseline: 1.0741x; 1.0731x over previous
//
#include <hip/hip_runtime.h>
#include <math.h>

#define HID 512
#define FEAT 128
#define SEQL 512
#define PREDL 128
#define NWG 256
#define R0 648   // teacher LDS row stride: 512 h + 128 e + 8 pad (%32==8)
#define R1 520   // AR LDS row stride (%32==8)

__device__ __forceinline__ float sigf_(float x) { return 1.0f / (1.0f + __expf(-x)); }
__device__ __forceinline__ float tanh_(float x) {
  float ax = fabsf(x);
  float e2 = __expf(-2.0f * ax);
  return copysignf((1.0f - e2) / (1.0f + e2), x);
}
__device__ __forceinline__ void stg_sc(float* p, float v) {
  __hip_atomic_store(p, v, __ATOMIC_RELAXED, __HIP_MEMORY_SCOPE_AGENT);
}

// ---------------------------------------------------------------------------
// Producer-stamped barrier (round-8 verified): 32 groups x 8 WGs.
// WG slot s of group g stores flags[g*8+s]=phase after __syncthreads
// (vmcnt(0)-drained => h-stores at coherence point first).
// ---------------------------------------------------------------------------
__device__ __forceinline__ void bar_arr(int* __restrict__ bar, int grp,
                                        int slot, int phase, int tid) {
  __syncthreads();
  if (tid == 0)
    __hip_atomic_store(bar + grp * 8 + slot, phase, __ATOMIC_RELAXED,
                       __HIP_MEMORY_SCOPE_AGENT);
  asm volatile("" ::: "memory");
}
__device__ __forceinline__ void bar_wai(int* __restrict__ bar, int grp,
                                        int phase, int tid,
                                        int* __restrict__ ldsph) {
  asm volatile("" ::: "memory");
  if (tid < 64) {
    for (;;) {
      int v = phase;
      if (tid < 8)
        v = __hip_atomic_load(bar + grp * 8 + tid, __ATOMIC_RELAXED,
                              __HIP_MEMORY_SCOPE_AGENT);
      if (__ballot(v >= phase) == 0xFFFFFFFFFFFFFFFFULL) break;
      __builtin_amdgcn_s_sleep(1);
    }
    if (tid == 0)
      __hip_atomic_store(ldsph, phase, __ATOMIC_RELAXED,
                         __HIP_MEMORY_SCOPE_WORKGROUP);
  } else {
    float z = 1.0f;
    while (__hip_atomic_load(ldsph, __ATOMIC_RELAXED,
                             __HIP_MEMORY_SCOPE_WORKGROUP) < phase) {
#pragma unroll
      for (int i = 0; i < 64; ++i) z = __builtin_fmaf(z, 1.0000001f, 1.0e-9f);
      asm volatile("" : "+v"(z));
    }
  }
  __syncthreads();
}

// coherent 1-float4 load, fused wait (verified pattern)
__device__ __forceinline__ void load1(const float4* p, float4& r) {
  asm volatile("global_load_dwordx4 %0, %1, off sc0 sc1\n\ts_waitcnt vmcnt(0)"
               : "=&v"(r) : "v"(p) : "memory");
}
// issue-only (wait via explicit s_waitcnt after shadow work)
__device__ __forceinline__ void issue1(const float4* p, float4& r) {
  asm volatile("global_load_dwordx4 %0, %1, off sc0 sc1"
               : "=&v"(r) : "v"(p) : "memory");
}

// ---------------------------------------------------------------------------
// Teacher: 256 WG x 1024 thr. grp = wg>>3 (4 batches), slot = wg&7 (64 units).
// Thread (g = tid>>8, ul = (tid>>2)&63, b = tid&3): computes gate g of unit
// slot*64+ul for batch b — LSTM0(t) (K=640: h0(t-1)+e(t)) AND LSTM1(t-1)
// (K=1024: h0(t-1), h1(t-2)). Gates combined via LDS; c in registers.
// ---------------------------------------------------------------------------
__global__ __launch_bounds__(1024, 1) void k_teacher(
    const float* __restrict__ x, const float* __restrict__ ENCW,
    const float* __restrict__ enc_b,
    const float* __restrict__ W0T, const float* __restrict__ W1F,
    const float* __restrict__ bih0, const float* __restrict__ bhh0,
    const float* __restrict__ bih1, const float* __restrict__ bhh1,
    float* __restrict__ h0A, float* __restrict__ h0B,
    float* __restrict__ h1A, float* __restrict__ h1B,
    float* __restrict__ cbuf, int* __restrict__ bar) {
  __shared__ float h0l[4 * R0];
  __shared__ float h1l[4 * R0];
  __shared__ float xl[4 * 132];
  __shared__ float sg0[1024];
  __shared__ float sg1[1024];
  __shared__ int lds_ph;

  const int wg = blockIdx.x, tid = threadIdx.x;
  const int grp = wg >> 3, slot = wg & 7;
  const int b = tid & 3, ul = (tid >> 2) & 63, g = tid >> 8;
  const int n = g * 512 + slot * 64 + ul;
  const int rowoff = n;  // float4 row offset inside W0T/W1F

  float* h0b[2] = {h0A, h0B};
  float* h1b[2] = {h1A, h1B};
  const float4* W0 = (const float4*)W0T + rowoff;
  const float4* W1 = (const float4*)W1F + rowoff;
  const float4* E4 = (const float4*)ENCW;

  const float bt0 = bih0[n] + bhh0[n];
  const float b1f = bih1[n] + bhh1[n];

  const int ldh0 = (tid < 512);
  const int lu = tid & 511;
  const int fe = (tid >> 2) & 127, be = tid & 3;  // encoder role (tid<512)
  const float encb = enc_b[fe];

  const float* h0row = h0l + b * R0;
  const float* h1row = h1l + b * R0;

  float c_reg = 0.0f;
  int ph = 0;
  if (tid == 0) lds_ph = 0;
  if (tid < 128) {
    const int bx = tid >> 5, f4 = tid & 31;
    *(float4*)(xl + bx * 132 + f4 * 4) =
        *(const float4*)(x + ((size_t)(grp * 4 + bx) * SEQL + 0) * FEAT + f4 * 4);
  }
  __syncthreads();

  for (int t = 0; t < SEQL; ++t) {
    // --- issue coherent h load (1 float4/thread) --------------------------
    const float* src = (ldh0 ? h0b[(t + 1) & 1] : h1b[t & 1]) + grp * 2048;
    const float4* sp = (const float4*)src + lu;
    float4 r;
    issue1(sp, r);

    // --- encoder in load shadow (tid<512): e -> h0l rows, cols 512..639 ---
    if (tid < 512) {
      float e = encb;
#pragma unroll 8
      for (int k4 = 0; k4 < 32; ++k4) {
        const float4 w = E4[k4 * 128 + fe];
        const float4 xv = *(const float4*)(xl + be * 132 + k4 * 4);
        e += w.x * xv.x + w.y * xv.y + w.z * xv.z + w.w * xv.w;
      }
      h0l[be * R0 + 512 + fe] = e;
    }
    asm volatile("s_waitcnt vmcnt(0)" ::: "memory");
    float* dl = ldh0 ? h0l : h1l;
    dl[0 * R0 + lu] = r.x; dl[1 * R0 + lu] = r.y;
    dl[2 * R0 + lu] = r.z; dl[3 * R0 + lu] = r.w;
    __syncthreads();

    // --- LSTM0(t): K=640 over h0row ---------------------------------------
    float a0 = bt0, a0b = 0.f;
#pragma unroll 4
    for (int k4 = 0; k4 < 160; ++k4) {
      const float4 w = W0[(size_t)k4 * 2048];
      const float4 h = *(const float4*)(h0row + k4 * 4);
      a0 = __builtin_fmaf(w.x, h.x, a0);
      a0b = __builtin_fmaf(w.y, h.y, a0b);
      a0 = __builtin_fmaf(w.z, h.z, a0);
      a0b = __builtin_fmaf(w.w, h.w, a0b);
    }
    a0 += a0b;
    // --- LSTM1(t-1): wih1 @ h0(t-1) then whh1 @ h1(t-2) -------------------
    float a1 = b1f, a1b = 0.f;
#pragma unroll 4
    for (int k4 = 0; k4 < 128; ++k4) {
      const float4 w = W1[(size_t)k4 * 2048];
      const float4 h = *(const float4*)(h0row + k4 * 4);
      a1 = __builtin_fmaf(w.x, h.x, a1);
      a1b = __builtin_fmaf(w.y, h.y, a1b);
      a1 = __builtin_fmaf(w.z, h.z, a1);
      a1b = __builtin_fmaf(w.w, h.w, a1b);
    }
#pragma unroll 4
    for (int k4 = 0; k4 < 128; ++k4) {
      const float4 w = W1[(size_t)(128 + k4) * 2048];
      const float4 h = *(const float4*)(h1row + k4 * 4);
      a1 = __builtin_fmaf(w.x, h.x, a1);
      a1b = __builtin_fmaf(w.y, h.y, a1b);
      a1 = __builtin_fmaf(w.z, h.z, a1);
      a1b = __builtin_fmaf(w.w, h.w, a1b);
    }
    a1 += a1b;
    sg0[tid] = a0;
    sg1[tid] = a1;
    __syncthreads();

    if (tid < 256) {  // combine LSTM0, own c0
      const float ig = sigf_(sg0[tid]), fg = sigf_(sg0[256 + tid]);
      const float gg = tanh_(sg0[512 + tid]), og = sigf_(sg0[768 + tid]);
      const float cn = fg * c_reg + ig * gg;
      c_reg = cn;
      stg_sc(h0b[t & 1] + grp * 2048 + slot * 256 + tid, og * tanh_(cn));
    } else if (tid < 512 && t > 0) {  // combine LSTM1(t-1), own c1
      const int l = tid - 256;
      const float ig = sigf_(sg1[l]), fg = sigf_(sg1[256 + l]);
      const float gg = tanh_(sg1[512 + l]), og = sigf_(sg1[768 + l]);
      const float cn = fg * c_reg + ig * gg;
      c_reg = cn;
      stg_sc(h1b[(t + 1) & 1] + grp * 2048 + slot * 256 + l, og * tanh_(cn));
    }
    bar_arr(bar, grp, slot, ++ph, tid);
    if (tid < 128 && t + 1 < SEQL) {
      const int bx = tid >> 5, f4 = tid & 31;
      *(float4*)(xl + bx * 132 + f4 * 4) =
          *(const float4*)(x + ((size_t)(grp * 4 + bx) * SEQL + (t + 1)) * FEAT + f4 * 4);
    }
    bar_wai(bar, grp, ph, tid, &lds_ph);
  }

  if (tid < 256) cbuf[(size_t)wg * 256 + tid] = c_reg;
  else if (tid < 512) cbuf[65536 + (size_t)wg * 256 + (tid - 256)] = c_reg;
}

// ---------------------------------------------------------------------------
// AR: LSTM1(511); then 127 x { LSTM0-AR(t)+decode(t-1) ; LSTM1(t) }; decode.
// ---------------------------------------------------------------------------
__global__ __launch_bounds__(1024, 1) void k_ar(
    const float* __restrict__ WAF, const float* __restrict__ W1F,
    const float* __restrict__ DECW, const float* __restrict__ dec_b,
    const float* __restrict__ bih0, const float* __restrict__ bhh0,
    const float* __restrict__ bih1, const float* __restrict__ bhh1,
    const float* __restrict__ bcomp,
    float* __restrict__ h0A, float* __restrict__ h0B,
    float* __restrict__ h1A, float* __restrict__ h1B,
    float* __restrict__ cbuf, int* __restrict__ bar,
    float* __restrict__ out) {
  __shared__ float hAl[4 * R1];  // h1-side tile
  __shared__ float hBl[4 * R1];  // h0-side tile
  __shared__ float sg0[1024];
  __shared__ float sg1[1024];
  __shared__ float sdec[256];
  __shared__ int lds_ph;

  const int wg = blockIdx.x, tid = threadIdx.x;
  const int grp = wg >> 3, slot = wg & 7;
  const int b = tid & 3, ul = (tid >> 2) & 63, g = tid >> 8;
  const int n = g * 512 + slot * 64 + ul;

  float* h0b[2] = {h0A, h0B};
  float* h1b[2] = {h1A, h1B};
  const float4* WA = (const float4*)WAF + n;
  const float4* W1 = (const float4*)W1F + n;
  const float4* D4 = (const float4*)DECW;

  const float baf = bih0[n] + bhh0[n] + bcomp[n];
  const float b1f = bih1[n] + bhh1[n];

  const int lu = tid & 511;
  const float* hArow = hAl + b * R1;
  const float* hBrow = hBl + b * R1;

  // decode role: threads 512..767
  const int d = tid - 512;
  const int dfl = d & 15, dbb = (d >> 4) & 3, dq = (d >> 6) & 3;
  const int fdec = slot * 16 + dfl;
  const float decb = dec_b[fdec & 127];

  float c_reg = 0.0f;
  if (tid < 256) c_reg = cbuf[(size_t)wg * 256 + tid];
  else if (tid < 512) c_reg = cbuf[65536 + (size_t)wg * 256 + (tid - 256)];

  int ph = 0;
  if (tid == 0) lds_ph = 0;
  __syncthreads();

  // ---- pre-phase: LSTM1(511) = f(h0(511)=h0b[1], h1(510)=h1b[0]) ---------
  {
    const float* src = (tid < 512 ? h0b[1] : h1b[0]) + grp * 2048;
    float4 r;
    load1((const float4*)src + lu, r);
    float* dl = (tid < 512) ? hBl : hAl;
    dl[0 * R1 + lu] = r.x; dl[1 * R1 + lu] = r.y;
    dl[2 * R1 + lu] = r.z; dl[3 * R1 + lu] = r.w;
    __syncthreads();
    float a1 = b1f, a1b = 0.f;
#pragma unroll 4
    for (int k4 = 0; k4 < 128; ++k4) {
      const float4 w = W1[(size_t)k4 * 2048];
      const float4 h = *(const float4*)(hBrow + k4 * 4);
      a1 = __builtin_fmaf(w.x, h.x, a1);  a1b = __builtin_fmaf(w.y, h.y, a1b);
      a1 = __builtin_fmaf(w.z, h.z, a1);  a1b = __builtin_fmaf(w.w, h.w, a1b);
    }
#pragma unroll 4
    for (int k4 = 0; k4 < 128; ++k4) {
      const float4 w = W1[(size_t)(128 + k4) * 2048];
      const float4 h = *(const float4*)(hArow + k4 * 4);
      a1 = __builtin_fmaf(w.x, h.x, a1);  a1b = __builtin_fmaf(w.y, h.y, a1b);
      a1 = __builtin_fmaf(w.z, h.z, a1);  a1b = __builtin_fmaf(w.w, h.w, a1b);
    }
    sg1[tid] = a1 + a1b;
    __syncthreads();
    if (tid >= 256 && tid < 512) {
      const int l = tid - 256;
      const float ig = sigf_(sg1[l]), fg = sigf_(sg1[256 + l]);
      const float gg = tanh_(sg1[512 + l]), og = sigf_(sg1[768 + l]);
      const float cn = fg * c_reg + ig * gg;
      c_reg = cn;
      stg_sc(h1b[1] + grp * 2048 + slot * 256 + l, og * tanh_(cn));
    }
    bar_arr(bar, grp, slot, ++ph, tid);
    bar_wai(bar, grp, ph, tid, &lds_ph);
  }

  // ---- AR loop ------------------------------------------------------------
  for (int t = SEQL; t < SEQL + PREDL - 1; ++t) {
    // phase 1: LSTM0-AR(t) over (h1(t-1), h0(t-1)); decode h1(t-1)
    {
      const float* src = (tid < 512 ? h1b[(t + 1) & 1] : h0b[(t + 1) & 1]) + grp * 2048;
      float4 r;
      load1((const float4*)src + lu, r);
      float* dl = (tid < 512) ? hAl : hBl;
      dl[0 * R1 + lu] = r.x; dl[1 * R1 + lu] = r.y;
      dl[2 * R1 + lu] = r.z; dl[3 * R1 + lu] = r.w;
      __syncthreads();
      float aA = baf, aAb = 0.f;
#pragma unroll 4
      for (int k4 = 0; k4 < 128; ++k4) {   // Wcomp @ h1(t-1)
        const float4 w = WA[(size_t)k4 * 2048];
        const float4 h = *(const float4*)(hArow + k4 * 4);
        aA = __builtin_fmaf(w.x, h.x, aA);  aAb = __builtin_fmaf(w.y, h.y, aAb);
        aA = __builtin_fmaf(w.z, h.z, aA);  aAb = __builtin_fmaf(w.w, h.w, aAb);
      }
#pragma unroll 4
      for (int k4 = 0; k4 < 128; ++k4) {   // whh0 @ h0(t-1)
        const float4 w = WA[(size_t)(128 + k4) * 2048];
        const float4 h = *(const float4*)(hBrow + k4 * 4);
        aA = __builtin_fmaf(w.x, h.x, aA);  aAb = __builtin_fmaf(w.y, h.y, aAb);
        aA = __builtin_fmaf(w.z, h.z, aA);  aAb = __builtin_fmaf(w.w, h.w, aAb);
      }
      sg0[tid] = aA + aAb;
      if (tid >= 512 && tid < 768) {  // decode partial over h1(t-1)
        float p = 0.f;
        const float* hr = hAl + dbb * R1;
#pragma unroll 4
        for (int k4 = dq * 32; k4 < dq * 32 + 32; ++k4) {
          const float4 w = D4[k4 * 128 + fdec];
          const float4 h = *(const float4*)(hr + k4 * 4);
          p += w.x * h.x + w.y * h.y + w.z * h.z + w.w * h.w;
        }
        sdec[d] = p;
      }
      __syncthreads();
      if (tid < 256) {
        const float ig = sigf_(sg0[tid]), fg = sigf_(sg0[256 + tid]);
        const float gg = tanh_(sg0[512 + tid]), og = sigf_(sg0[768 + tid]);
        const float cn = fg * c_reg + ig * gg;
        c_reg = cn;
        stg_sc(h0b[t & 1] + grp * 2048 + slot * 256 + tid, og * tanh_(cn));
      }
      if (tid >= 512 && tid < 576) {  // dq==0 threads: sum + store
        const float s = decb + sdec[d] + sdec[d + 64] + sdec[d + 128] + sdec[d + 192];
        out[((size_t)(grp * 4 + dbb) * PREDL + (t - SEQL)) * FEAT + fdec] = s;
      }
      bar_arr(bar, grp, slot, ++ph, tid);
      bar_wai(bar, grp, ph, tid, &lds_ph);
    }
    // phase 2: LSTM1(t) over (h0(t), h1(t-1) still in hAl)
    {
      if (tid < 512) {
        const float* src = h0b[t & 1] + grp * 2048;
        float4 r;
        load1((const float4*)src + lu, r);
        hBl[0 * R1 + lu] = r.x; hBl[1 * R1 + lu] = r.y;
        hBl[2 * R1 + lu] = r.z; hBl[3 * R1 + lu] = r.w;
      }
      __syncthreads();
      float a1 = b1f, a1b = 0.f;
#pragma unroll 4
      for (int k4 = 0; k4 < 128; ++k4) {   // wih1 @ h0(t)
        const float4 w = W1[(size_t)k4 * 2048];
        const float4 h = *(const float4*)(hBrow + k4 * 4);
        a1 = __builtin_fmaf(w.x, h.x, a1);  a1b = __builtin_fmaf(w.y, h.y, a1b);
        a1 = __builtin_fmaf(w.z, h.z, a1);  a1b = __builtin_fmaf(w.w, h.w, a1b);
      }
#pragma unroll 4
      for (int k4 = 0; k4 < 128; ++k4) {   // whh1 @ h1(t-1)
        const float4 w = W1[(size_t)(128 + k4) * 2048];
        const float4 h = *(const float4*)(hArow + k4 * 4);
        a1 = __builtin_fmaf(w.x, h.x, a1);  a1b = __builtin_fmaf(w.y, h.y, a1b);
        a1 = __builtin_fmaf(w.z, h.z, a1);  a1b = __builtin_fmaf(w.w, h.w, a1b);
      }
      sg1[tid] = a1 + a1b;
      __syncthreads();
      if (tid >= 256 && tid < 512) {
        const int l = tid - 256;
        const float ig = sigf_(sg1[l]), fg = sigf_(sg1[256 + l]);
        const float gg = tanh_(sg1[512 + l]), og = sigf_(sg1[768 + l]);
        const float cn = fg * c_reg + ig * gg;
        c_reg = cn;
        stg_sc(h1b[t & 1] + grp * 2048 + slot * 256 + l, og * tanh_(cn));
      }
      bar_arr(bar, grp, slot, ++ph, tid);
      bar_wai(bar, grp, ph, tid, &lds_ph);
    }
  }

  // ---- final decode: h1(638) = h1b[0], step 127 ---------------------------
  {
    if (tid < 512) {
      const float* src = h1b[0] + grp * 2048;
      float4 r;
      load1((const float4*)src + lu, r);
      hAl[0 * R1 + lu] = r.x; hAl[1 * R1 + lu] = r.y;
      hAl[2 * R1 + lu] = r.z; hAl[3 * R1 + lu] = r.w;
    }
    __syncthreads();
    if (tid >= 512 && tid < 768) {
      float p = 0.f;
      const float* hr = hAl + dbb * R1;
#pragma unroll 4
      for (int k4 = dq * 32; k4 < dq * 32 + 32; ++k4) {
        const float4 w = D4[k4 * 128 + fdec];
        const float4 h = *(const float4*)(hr + k4 * 4);
        p += w.x * h.x + w.y * h.y + w.z * h.z + w.w * h.w;
      }
      sdec[d] = p;
    }
    __syncthreads();
    if (tid >= 512 && tid < 576) {
      const float s = decb + sdec[d] + sdec[d + 64] + sdec[d + 128] + sdec[d + 192];
      out[((size_t)(grp * 4 + dbb) * PREDL + (PREDL - 1)) * FEAT + fdec] = s;
    }
  }
}

// ===== prologue ============================================================
__global__ void k_b1(const float* __restrict__ enc_w,
                     const float* __restrict__ dec_w, float* __restrict__ B1) {
  const int idx = blockIdx.x * 256 + threadIdx.x;
  const int j = idx >> 9, m = idx & 511;
  float acc = 0.0f;
  for (int k = 0; k < FEAT; ++k) acc += enc_w[j * FEAT + k] * dec_w[k * HID + m];
  B1[idx] = acc;
}
__global__ void k_te(const float* __restrict__ enc_w,
                     const float* __restrict__ enc_b,
                     const float* __restrict__ dec_b, float* __restrict__ te) {
  const int j = threadIdx.x;
  float acc = enc_b[j];
  for (int k = 0; k < FEAT; ++k) acc += dec_b[k] * enc_w[j * FEAT + k];
  te[j] = acc;
}
__global__ void k_bcomp(const float* __restrict__ wih0,
                        const float* __restrict__ te, float* __restrict__ bc) {
  const int nn = blockIdx.x * 256 + threadIdx.x;
  float acc = 0.0f;
  for (int j = 0; j < FEAT; ++j) acc += wih0[nn * FEAT + j] * te[j];
  bc[nn] = acc;
}
// W0T[k4*2048 + n] f4: k<512 -> whh0[n][k..], else wih0[n][k-512..]  (1280 blk)
__global__ void k_w0t(const float* __restrict__ whh0,
                      const float* __restrict__ wih0, float* __restrict__ W) {
  const int idx = blockIdx.x * 256 + threadIdx.x;
  const int k4 = idx >> 11, rr = idx & 2047;
  const int k = k4 * 4;
  float4 v;
  if (k < 512) {
    const float* p = whh0 + (size_t)rr * 512 + k;
    v = make_float4(p[0], p[1], p[2], p[3]);
  } else {
    const float* p = wih0 + (size_t)rr * 128 + (k - 512);
    v = make_float4(p[0], p[1], p[2], p[3]);
  }
  ((float4*)W)[idx] = v;
}
// W1F[k4*2048 + n] f4: k<512 -> wih1, else whh1  (2048 blk)
__global__ void k_w1f(const float* __restrict__ wih1,
                      const float* __restrict__ whh1, float* __restrict__ W) {
  const int idx = blockIdx.x * 256 + threadIdx.x;
  const int k4 = idx >> 11, rr = idx & 2047;
  const int k = k4 * 4;
  const float* p = (k < 512) ? (wih1 + (size_t)rr * 512 + k)
                             : (whh1 + (size_t)rr * 512 + (k - 512));
  ((float4*)W)[idx] = make_float4(p[0], p[1], p[2], p[3]);
}
// WAF[k4*2048 + n] f4: k<512 -> Wcomp row (on-the-fly via B1), else whh0
__global__ void k_waf(const float* __restrict__ wih0,
                      const float* __restrict__ B1,
                      const float* __restrict__ whh0, float* __restrict__ W) {
  const int idx = blockIdx.x * 256 + threadIdx.x;
  const int k4 = idx >> 11, rr = idx & 2047;
  const int k = k4 * 4;
  float4 v;
  if (k < 512) {
    float s0 = 0, s1 = 0, s2 = 0, s3 = 0;
    const float* wr = wih0 + (size_t)rr * 128;
    for (int j = 0; j < 128; ++j) {
      const float wv = wr[j];
      const float* bp = B1 + (size_t)j * 512 + k;
      s0 += wv * bp[0]; s1 += wv * bp[1]; s2 += wv * bp[2]; s3 += wv * bp[3];
    }
    v = make_float4(s0, s1, s2, s3);
  } else {
    const float* p = whh0 + (size_t)rr * 512 + (k - 512);
    v = make_float4(p[0], p[1], p[2], p[3]);
  }
  ((float4*)W)[idx] = v;
}
// ENCW[k4*128+f] = enc_w[f][k4*4..]  (16 blk)
__global__ void k_encw(const float* __restrict__ enc_w, float* __restrict__ W) {
  const int idx = blockIdx.x * 256 + threadIdx.x;
  const int k4 = idx >> 7, f = idx & 127;
  const float* p = enc_w + (size_t)f * 128 + k4 * 4;
  ((float4*)W)[idx] = make_float4(p[0], p[1], p[2], p[3]);
}
// DECW[k4*128+f] = dec_w[f][k4*4..]  (64 blk)
__global__ void k_decw(const float* __restrict__ dec_w, float* __restrict__ W) {
  const int idx = blockIdx.x * 256 + threadIdx.x;
  const int k4 = idx >> 7, f = idx & 127;
  const float* p = dec_w + (size_t)f * 512 + k4 * 4;
  ((float4*)W)[idx] = make_float4(p[0], p[1], p[2], p[3]);
}

// ===== ws layout (floats) ==================================================
#define WS_H0A 0
#define WS_H0B 65536
#define WS_H1A 131072
#define WS_H1B 196608
#define WS_CBUF 262144
#define WS_BART 393216
#define WS_BARA 397312
#define WS_TE 401408
#define WS_BCOMP 401536
#define WS_B1 403584
#define WS_ENCW 469120
#define WS_DECW 485504
#define WS_W0T 551040
#define WS_W1F 1861760
#define WS_WAF 3958912
// end 6056064 floats = 24.2 MB

extern "C" void kernel_launch(void* const* d_in, const int* in_sizes, int n_in,
                              void* d_out, int out_size, void* d_ws,
                              size_t ws_size, hipStream_t stream) {
  const float* x     = (const float*)d_in[0];
  const float* enc_w = (const float*)d_in[1];
  const float* enc_b = (const float*)d_in[2];
  const float* dec_w = (const float*)d_in[3];
  const float* dec_b = (const float*)d_in[4];
  const float* wih0  = (const float*)d_in[5];
  const float* whh0  = (const float*)d_in[6];
  const float* bih0  = (const float*)d_in[7];
  const float* bhh0  = (const float*)d_in[8];
  const float* wih1  = (const float*)d_in[9];
  const float* whh1  = (const float*)d_in[10];
  const float* bih1  = (const float*)d_in[11];
  const float* bhh1  = (const float*)d_in[12];
  float* out = (float*)d_out;

  float* ws = (float*)d_ws;
  float* h0A = ws + WS_H0A;
  float* h0B = ws + WS_H0B;
  float* h1A = ws + WS_H1A;
  float* h1B = ws + WS_H1B;
  float* cbuf = ws + WS_CBUF;
  int* barT = (int*)(ws + WS_BART);
  int* barA = (int*)(ws + WS_BARA);
  float* te = ws + WS_TE;
  float* bcomp = ws + WS_BCOMP;
  float* B1 = ws + WS_B1;
  float* ENCW = ws + WS_ENCW;
  float* DECW = ws + WS_DECW;
  float* W0T = ws + WS_W0T;
  float* W1F = ws + WS_W1F;
  float* WAF = ws + WS_WAF;

  // zero h states + barrier flags each launch
  (void)hipMemsetAsync(ws, 0, (size_t)262144 * sizeof(float), stream);
  (void)hipMemsetAsync(ws + WS_BART, 0, (size_t)8192 * sizeof(float), stream);

  k_b1<<<256, 256, 0, stream>>>(enc_w, dec_w, B1);
  k_te<<<1, 128, 0, stream>>>(enc_w, enc_b, dec_b, te);
  k_bcomp<<<8, 256, 0, stream>>>(wih0, te, bcomp);
  k_w0t<<<1280, 256, 0, stream>>>(whh0, wih0, W0T);
  k_w1f<<<2048, 256, 0, stream>>>(wih1, whh1, W1F);
  k_waf<<<2048, 256, 0, stream>>>(wih0, B1, whh0, WAF);
  k_encw<<<16, 256, 0, stream>>>(enc_w, ENCW);
  k_decw<<<64, 256, 0, stream>>>(dec_w, DECW);

  k_teacher<<<NWG, 1024, 0, stream>>>(
      x, ENCW, enc_b, W0T, W1F, bih0, bhh0, bih1, bhh1,
      h0A, h0B, h1A, h1B, cbuf, barT);

  k_ar<<<NWG, 1024, 0, stream>>>(
      WAF, W1F, DECW, dec_b, bih0, bhh0, bih1, bhh1, bcomp,
      h0A, h0B, h1A, h1B, cbuf, barA, out);
}